// Round 3
// baseline (335.817 us; speedup 1.0000x reference)
//
#include <hip/hip_runtime.h>

// SSIM loss, streaming-row kernel, no LDS in the hot loop, no barriers.
// r5: 1 col/thread, 55 rolling accumulators, grid 16x2x96.
// r6: pinned waves_per_eu(4,4) -> no change. VGPR stayed 64, WRITE 28.5MB.
// r7 diagnosis: the W[12] init loop had NO #pragma unroll -> runtime-indexed
// store -> SROA killed -> W lived in SCRATCH all kernel (12 scratch stores x
// 786k threads = 37MB ~ observed WRITE_SIZE; 12 scratch LOADS per phase on
// the critical path capped VALUBusy at 66% and left regalloc at 64 VGPR).
// Fix: build W with 12 explicit literal-index assignments. Rule #20.
// Odd-column alignment via per-lane 12-tap weight vector W (parity-shifted
// Gaussian + zero pad tap): loads stay 8B-aligned float2, all array indices
// literal (SROA), no divergence, fmaf(0,x,h)==h keeps the blur bit-exact
// vs the 11-tap order (absmax 0.0 r5/r6).

#define IMG 512
#define OUT_DIM 502    // 512 - 10 (VALID conv twice)
#define WIN 11
#define BH 32          // output rows per band
#define NPHASE (BH + WIN - 1)   // 42
#define NPLANES 96

template<int PH>
__device__ __forceinline__ void phase_step(int base, int r0, int c, int cbase,
                                           const float* __restrict__ Xp,
                                           const float* __restrict__ Yp,
                                           const float (&W)[12],
                                           float (&a)[5][WIN], float& local) {
    // Gaussian(11, sigma=1.5), normalized; matches numpy fp32 (absmax 0.0).
    constexpr float G[WIN] = {0.00102838f, 0.00759875f, 0.03600077f, 0.10936071f,
                              0.21300553f, 0.26601172f, 0.21300553f, 0.10936071f,
                              0.03600077f, 0.00759875f, 0.00102838f};
    const int p = base + PH;
    if (p >= NPHASE) return;                  // uniform; only last outer iter
    const int rr = min(r0 + p, IMG - 1);      // clamped rows feed only discarded outputs
    const float* px = Xp + rr * IMG + cbase;
    const float* py = Yp + rr * IMG + cbase;

    float x[12], y[12];
    #pragma unroll
    for (int i = 0; i < 6; ++i) {             // 12 aligned float2 loads; halo -> L1
        const float2 xv = *(const float2*)(px + 2 * i);
        const float2 yv = *(const float2*)(py + 2 * i);
        x[2 * i] = xv.x; x[2 * i + 1] = xv.y;
        y[2 * i] = yv.x; y[2 * i + 1] = yv.y;
    }

    // Horizontal blur, 12 taps with per-lane parity-shifted weights.
    // Even lane: W = {G0..G10, 0}; odd lane: W = {0, G0..G10}. The zero tap
    // contributes fmaf(0,v,h)==h exactly -> bit-identical to 11-tap order.
    float h0 = 0.f, h1 = 0.f, h2 = 0.f, h3 = 0.f, h4 = 0.f;
    #pragma unroll
    for (int k = 0; k < 12; ++k) {
        const float w = W[k];
        h0 = fmaf(w, x[k], h0);
        h1 = fmaf(w, y[k], h1);
        const float xx = x[k] * x[k];
        h2 = fmaf(w, xx, h2);
        const float yy = y[k] * y[k];
        h3 = fmaf(w, yy, h3);
        const float xy = x[k] * y[k];
        h4 = fmaf(w, xy, h4);
    }

    // Row r contributes weight G[d] to output row r-d; slot (p-d) mod 11.
    // d==0 ASSIGNS its slot (freed by last phase's emit) -> no init/reset.
    #pragma unroll
    for (int d = 0; d < WIN; ++d) {
        const int s = (PH - d + 2 * WIN) % WIN;   // literal constant after unroll
        const float g = G[d];
        a[0][s] = (d == 0) ? (g * h0) : fmaf(g, h0, a[0][s]);
        a[1][s] = (d == 0) ? (g * h1) : fmaf(g, h1, a[1][s]);
        a[2][s] = (d == 0) ? (g * h2) : fmaf(g, h2, a[2][s]);
        a[3][s] = (d == 0) ? (g * h3) : fmaf(g, h3, a[3][s]);
        a[4][s] = (d == 0) ? (g * h4) : fmaf(g, h4, a[4][s]);
    }

    // Output row o = r-10 completed this phase; its slot is (PH+1)%11.
    if (p >= WIN - 1) {
        const int o = r0 + p - (WIN - 1);
        if (o < OUT_DIM && c < OUT_DIM) {
            constexpr int se = (PH + 1) % WIN;
            const float C1 = 0.0001f, C2 = 0.0009f;
            const float m1 = a[0][se], m2 = a[1][se];
            const float m1sq = m1 * m1, m2sq = m2 * m2, m12 = m1 * m2;
            const float s1  = a[2][se] - m1sq;
            const float s2  = a[3][se] - m2sq;
            const float s12 = a[4][se] - m12;
            const float num = (2.f * m12 + C1) * (2.f * s12 + C2);
            const float den = (m1sq + m2sq + C1) * (s1 + s2 + C2);
            local += num * __builtin_amdgcn_rcpf(den);
        }
    }
}

__global__ __launch_bounds__(256)
__attribute__((amdgpu_waves_per_eu(4, 4)))   // pin: 128-VGPR budget, no spill-down
void ssim_stream(const float* __restrict__ X,
                 const float* __restrict__ Y,
                 float* __restrict__ planeSums) {
    constexpr float G[WIN] = {0.00102838f, 0.00759875f, 0.03600077f, 0.10936071f,
                              0.21300553f, 0.26601172f, 0.21300553f, 0.10936071f,
                              0.03600077f, 0.00759875f, 0.00102838f};
    const int tid = threadIdx.x;
    const int r0 = blockIdx.x * BH;
    const int c = (blockIdx.y << 8) + tid;    // this lane's single output col
    const int plane = blockIdx.z;
    const size_t pbase = (size_t)plane * IMG * IMG;
    const float* Xp = X + pbase;
    const float* Yp = Y + pbase;
    const int cbase = min(c & ~1, IMG - 12);  // aligned window base; clamp keeps
                                              // loads in-bounds, clamped lanes never emit

    // Per-lane 12-tap weights: even = {G,0}, odd = {0,G}.
    // Rule #20: NO loop here — 12 explicit literal-index stores, or SROA dies
    // and W lives in scratch (r5/r6: 28-31MB WRITE_SIZE, 12 scratch loads/phase).
    float W[12];
    const bool odd = (c & 1) != 0;
    W[0]  = odd ? 0.f   : G[0];
    W[1]  = odd ? G[0]  : G[1];
    W[2]  = odd ? G[1]  : G[2];
    W[3]  = odd ? G[2]  : G[3];
    W[4]  = odd ? G[3]  : G[4];
    W[5]  = odd ? G[4]  : G[5];
    W[6]  = odd ? G[5]  : G[6];
    W[7]  = odd ? G[6]  : G[7];
    W[8]  = odd ? G[7]  : G[8];
    W[9]  = odd ? G[8]  : G[9];
    W[10] = odd ? G[9]  : G[10];
    W[11] = odd ? G[10] : 0.f;

    float a[5][WIN];                          // 55 regs once SROA'd
    float local = 0.f;

    for (int base = 0; base < 44; base += WIN) {  // 4 x 11 phases, guard trims to 42
        phase_step<0>(base, r0, c, cbase, Xp, Yp, W, a, local);
        phase_step<1>(base, r0, c, cbase, Xp, Yp, W, a, local);
        phase_step<2>(base, r0, c, cbase, Xp, Yp, W, a, local);
        phase_step<3>(base, r0, c, cbase, Xp, Yp, W, a, local);
        phase_step<4>(base, r0, c, cbase, Xp, Yp, W, a, local);
        phase_step<5>(base, r0, c, cbase, Xp, Yp, W, a, local);
        phase_step<6>(base, r0, c, cbase, Xp, Yp, W, a, local);
        phase_step<7>(base, r0, c, cbase, Xp, Yp, W, a, local);
        phase_step<8>(base, r0, c, cbase, Xp, Yp, W, a, local);
        phase_step<9>(base, r0, c, cbase, Xp, Yp, W, a, local);
        phase_step<10>(base, r0, c, cbase, Xp, Yp, W, a, local);
    }

    // Block reduction -> one atomic per block (32 blocks/plane).
    #pragma unroll
    for (int off = 32; off > 0; off >>= 1)
        local += __shfl_down(local, off, 64);
    __shared__ float red[4];
    if ((tid & 63) == 0) red[tid >> 6] = local;
    __syncthreads();
    if (tid == 0)
        atomicAdd(&planeSums[plane], (red[0] + red[1]) + (red[2] + red[3]));
}

__global__ __launch_bounds__(128) void ssim_finalize(const float* __restrict__ planeSums,
                                                     float* __restrict__ out) {
    const int tid = threadIdx.x;
    float v = 0.f;
    if (tid < NPLANES) {
        const float m = planeSums[tid] * (1.0f / (float)(OUT_DIM * OUT_DIM));
        v = fmaxf(m, 0.f);   // nonnegative_ssim relu
    }
    #pragma unroll
    for (int off = 32; off > 0; off >>= 1)
        v += __shfl_down(v, off, 64);
    __shared__ float red[2];
    if ((tid & 63) == 0) red[tid >> 6] = v;
    __syncthreads();
    if (tid == 0) out[0] = 1.0f - (red[0] + red[1]) * (1.0f / (float)NPLANES);
}

extern "C" void kernel_launch(void* const* d_in, const int* in_sizes, int n_in,
                              void* d_out, int out_size, void* d_ws, size_t ws_size,
                              hipStream_t stream) {
    const float* X = (const float*)d_in[0];   // predictions
    const float* Y = (const float*)d_in[1];   // labels
    float* out = (float*)d_out;
    float* ws  = (float*)d_ws;                // 96 per-plane sums

    hipMemsetAsync(ws, 0, NPLANES * sizeof(float), stream);

    dim3 grid((OUT_DIM + BH - 1) / BH, 2, NPLANES);   // 16 x 2 x 96 = 3072 blocks
    ssim_stream<<<grid, 256, 0, stream>>>(X, Y, ws);
    ssim_finalize<<<1, 128, 0, stream>>>(ws, out);
}

// Round 4
// 335.035 us; speedup vs baseline: 1.0023x; 1.0023x over previous
//
#include <hip/hip_runtime.h>

// SSIM loss, streaming-row kernel, no LDS in the hot loop, no barriers.
// r5: 1 col/thread, 55 rolling accumulators, grid 16x2x96.
// r6/r7: occupancy knobs + explicit W init -> NO change (VGPR pinned at 64,
// WRITE_SIZE ~28.8MB scratch residue, occupancy 40% = scratch-limited).
// Diagnosis: some local array still fails SROA -> alloca -> scratch; VGPR=64
// because the real working set never enters regalloc. Source inspection
// failed to find it 2x, so r8 removes the possibility class entirely:
//   - x, y, W -> NAMED SCALARS (pure SSA, alloca-impossible)
//   - a ring  -> every access through ACC/EMIT macros with true constexpr
//                indices (template PH + literal d)
// Algorithm unchanged: per-lane 12-tap parity-shifted Gaussian (zero pad tap,
// fmaf(0,x,h)==h -> bit-exact, absmax 0.0 r5-r7), aligned float2 loads,
// 11-slot rolling vertical accumulators, d==0 assigns (no init needed).

#define IMG 512
#define OUT_DIM 502    // 512 - 10 (VALID conv twice)
#define WIN 11
#define BH 32          // output rows per band
#define NPHASE (BH + WIN - 1)   // 42
#define NPLANES 96

#define GAUSS_INIT {0.00102838f, 0.00759875f, 0.03600077f, 0.10936071f, \
                    0.21300553f, 0.26601172f, 0.21300553f, 0.10936071f, \
                    0.03600077f, 0.00759875f, 0.00102838f}

template<int PH>
__device__ __forceinline__ void phase_step(
    int base, int r0, int c, int cbase,
    const float* __restrict__ Xp, const float* __restrict__ Yp,
    float w0, float w1, float w2, float w3, float w4, float w5,
    float w6, float w7, float w8, float w9, float w10, float w11,
    float (&a)[5][WIN], float& local) {
    constexpr float G[WIN] = GAUSS_INIT;   // matches numpy fp32 (absmax 0.0)
    const int p = base + PH;
    if (p >= NPHASE) return;               // uniform; only last outer iter
    const int rr = min(r0 + p, IMG - 1);   // clamped rows feed only discarded outputs
    const float* px = Xp + rr * IMG + cbase;
    const float* py = Yp + rr * IMG + cbase;

    // 12 aligned float2 loads; halo overlap -> L1. All named scalars (SSA).
    const float2 xv0 = *(const float2*)(px + 0);
    const float2 xv1 = *(const float2*)(px + 2);
    const float2 xv2 = *(const float2*)(px + 4);
    const float2 xv3 = *(const float2*)(px + 6);
    const float2 xv4 = *(const float2*)(px + 8);
    const float2 xv5 = *(const float2*)(px + 10);
    const float2 yv0 = *(const float2*)(py + 0);
    const float2 yv1 = *(const float2*)(py + 2);
    const float2 yv2 = *(const float2*)(py + 4);
    const float2 yv3 = *(const float2*)(py + 6);
    const float2 yv4 = *(const float2*)(py + 8);
    const float2 yv5 = *(const float2*)(py + 10);
    const float x0 = xv0.x, x1 = xv0.y, x2 = xv1.x, x3 = xv1.y;
    const float x4 = xv2.x, x5 = xv2.y, x6 = xv3.x, x7 = xv3.y;
    const float x8 = xv4.x, x9 = xv4.y, x10 = xv5.x, x11 = xv5.y;
    const float y0 = yv0.x, y1 = yv0.y, y2 = yv1.x, y3 = yv1.y;
    const float y4 = yv2.x, y5 = yv2.y, y6 = yv3.x, y7 = yv3.y;
    const float y8 = yv4.x, y9 = yv4.y, y10 = yv5.x, y11 = yv5.y;

    // Horizontal blur, 12 taps, parity-shifted weights (named scalars).
    float h0 = 0.f, h1 = 0.f, h2 = 0.f, h3 = 0.f, h4 = 0.f;
#define TAP(k) do {                                   \
        h0 = fmaf(w##k, x##k, h0);                    \
        h1 = fmaf(w##k, y##k, h1);                    \
        h2 = fmaf(w##k, x##k * x##k, h2);             \
        h3 = fmaf(w##k, y##k * y##k, h3);             \
        h4 = fmaf(w##k, x##k * y##k, h4);             \
    } while (0)
    TAP(0); TAP(1); TAP(2); TAP(3); TAP(4); TAP(5);
    TAP(6); TAP(7); TAP(8); TAP(9); TAP(10); TAP(11);
#undef TAP

    // Row r contributes weight G[d] to output row r-d; slot (p-d) mod 11.
    // d==0 ASSIGNS its slot (freed by last phase's emit) -> no init/reset.
    // Every index is a true constexpr (template PH + literal d).
#define ACC(d) do {                                               \
        constexpr int s = (PH - (d) + 2 * WIN) % WIN;             \
        constexpr float g = G[(d)];                               \
        if ((d) == 0) {                                           \
            a[0][s] = g * h0; a[1][s] = g * h1; a[2][s] = g * h2; \
            a[3][s] = g * h3; a[4][s] = g * h4;                   \
        } else {                                                  \
            a[0][s] = fmaf(g, h0, a[0][s]);                       \
            a[1][s] = fmaf(g, h1, a[1][s]);                       \
            a[2][s] = fmaf(g, h2, a[2][s]);                       \
            a[3][s] = fmaf(g, h3, a[3][s]);                       \
            a[4][s] = fmaf(g, h4, a[4][s]);                       \
        }                                                         \
    } while (0)
    ACC(0); ACC(1); ACC(2); ACC(3); ACC(4); ACC(5);
    ACC(6); ACC(7); ACC(8); ACC(9); ACC(10);
#undef ACC

    // Output row o = r-10 completed this phase; its slot is (PH+1)%11.
    if (p >= WIN - 1) {
        const int o = r0 + p - (WIN - 1);
        if (o < OUT_DIM && c < OUT_DIM) {
            constexpr int se = (PH + 1) % WIN;
            const float C1 = 0.0001f, C2 = 0.0009f;
            const float m1 = a[0][se], m2 = a[1][se];
            const float m1sq = m1 * m1, m2sq = m2 * m2, m12 = m1 * m2;
            const float s1  = a[2][se] - m1sq;
            const float s2  = a[3][se] - m2sq;
            const float s12 = a[4][se] - m12;
            const float num = (2.f * m12 + C1) * (2.f * s12 + C2);
            const float den = (m1sq + m2sq + C1) * (s1 + s2 + C2);
            local += num * __builtin_amdgcn_rcpf(den);
        }
    }
}

__global__ __launch_bounds__(256)
__attribute__((amdgpu_waves_per_eu(4, 4)))   // budget 128 VGPR, 4 waves/EU
void ssim_stream(const float* __restrict__ X,
                 const float* __restrict__ Y,
                 float* __restrict__ planeSums) {
    constexpr float G[WIN] = GAUSS_INIT;
    const int tid = threadIdx.x;
    const int r0 = blockIdx.x * BH;
    const int c = (blockIdx.y << 8) + tid;    // this lane's single output col
    const int plane = blockIdx.z;
    const size_t pbase = (size_t)plane * IMG * IMG;
    const float* Xp = X + pbase;
    const float* Yp = Y + pbase;
    const int cbase = min(c & ~1, IMG - 12);  // aligned window base; clamp keeps
                                              // loads in-bounds, clamped lanes never emit

    // Per-lane 12-tap weights: even = {G,0}, odd = {0,G}. Named scalars (SSA).
    const bool odd = (c & 1) != 0;
    const float w0  = odd ? 0.f   : G[0];
    const float w1  = odd ? G[0]  : G[1];
    const float w2  = odd ? G[1]  : G[2];
    const float w3  = odd ? G[2]  : G[3];
    const float w4  = odd ? G[3]  : G[4];
    const float w5  = odd ? G[4]  : G[5];
    const float w6  = odd ? G[5]  : G[6];
    const float w7  = odd ? G[6]  : G[7];
    const float w8  = odd ? G[7]  : G[8];
    const float w9  = odd ? G[8]  : G[9];
    const float w10 = odd ? G[9]  : G[10];
    const float w11 = odd ? G[10] : 0.f;

    float a[5][WIN];                          // 55 regs; all accesses constexpr-indexed
    float local = 0.f;

    for (int base = 0; base < 44; base += WIN) {  // 4 x 11 phases, guard trims to 42
        phase_step<0>(base, r0, c, cbase, Xp, Yp, w0,w1,w2,w3,w4,w5,w6,w7,w8,w9,w10,w11, a, local);
        phase_step<1>(base, r0, c, cbase, Xp, Yp, w0,w1,w2,w3,w4,w5,w6,w7,w8,w9,w10,w11, a, local);
        phase_step<2>(base, r0, c, cbase, Xp, Yp, w0,w1,w2,w3,w4,w5,w6,w7,w8,w9,w10,w11, a, local);
        phase_step<3>(base, r0, c, cbase, Xp, Yp, w0,w1,w2,w3,w4,w5,w6,w7,w8,w9,w10,w11, a, local);
        phase_step<4>(base, r0, c, cbase, Xp, Yp, w0,w1,w2,w3,w4,w5,w6,w7,w8,w9,w10,w11, a, local);
        phase_step<5>(base, r0, c, cbase, Xp, Yp, w0,w1,w2,w3,w4,w5,w6,w7,w8,w9,w10,w11, a, local);
        phase_step<6>(base, r0, c, cbase, Xp, Yp, w0,w1,w2,w3,w4,w5,w6,w7,w8,w9,w10,w11, a, local);
        phase_step<7>(base, r0, c, cbase, Xp, Yp, w0,w1,w2,w3,w4,w5,w6,w7,w8,w9,w10,w11, a, local);
        phase_step<8>(base, r0, c, cbase, Xp, Yp, w0,w1,w2,w3,w4,w5,w6,w7,w8,w9,w10,w11, a, local);
        phase_step<9>(base, r0, c, cbase, Xp, Yp, w0,w1,w2,w3,w4,w5,w6,w7,w8,w9,w10,w11, a, local);
        phase_step<10>(base, r0, c, cbase, Xp, Yp, w0,w1,w2,w3,w4,w5,w6,w7,w8,w9,w10,w11, a, local);
    }

    // Block reduction -> one atomic per block (32 blocks/plane).
    #pragma unroll
    for (int off = 32; off > 0; off >>= 1)
        local += __shfl_down(local, off, 64);
    __shared__ float red[4];
    if ((tid & 63) == 0) red[tid >> 6] = local;
    __syncthreads();
    if (tid == 0)
        atomicAdd(&planeSums[plane], (red[0] + red[1]) + (red[2] + red[3]));
}

__global__ __launch_bounds__(128) void ssim_finalize(const float* __restrict__ planeSums,
                                                     float* __restrict__ out) {
    const int tid = threadIdx.x;
    float v = 0.f;
    if (tid < NPLANES) {
        const float m = planeSums[tid] * (1.0f / (float)(OUT_DIM * OUT_DIM));
        v = fmaxf(m, 0.f);   // nonnegative_ssim relu
    }
    #pragma unroll
    for (int off = 32; off > 0; off >>= 1)
        v += __shfl_down(v, off, 64);
    __shared__ float red[2];
    if ((tid & 63) == 0) red[tid >> 6] = v;
    __syncthreads();
    if (tid == 0) out[0] = 1.0f - (red[0] + red[1]) * (1.0f / (float)NPLANES);
}

extern "C" void kernel_launch(void* const* d_in, const int* in_sizes, int n_in,
                              void* d_out, int out_size, void* d_ws, size_t ws_size,
                              hipStream_t stream) {
    const float* X = (const float*)d_in[0];   // predictions
    const float* Y = (const float*)d_in[1];   // labels
    float* out = (float*)d_out;
    float* ws  = (float*)d_ws;                // 96 per-plane sums

    hipMemsetAsync(ws, 0, NPLANES * sizeof(float), stream);

    dim3 grid((OUT_DIM + BH - 1) / BH, 2, NPLANES);   // 16 x 2 x 96 = 3072 blocks
    ssim_stream<<<grid, 256, 0, stream>>>(X, Y, ws);
    ssim_finalize<<<1, 128, 0, stream>>>(ws, out);
}